// Round 5
// baseline (327.009 us; speedup 1.0000x reference)
//
#include <hip/hip_runtime.h>
#include <hip/hip_bf16.h>

typedef float f32x4 __attribute__((ext_vector_type(4)));
typedef __bf16 bf16x8 __attribute__((ext_vector_type(8)));
typedef __bf16 bf16x4 __attribute__((ext_vector_type(4)));
typedef unsigned short u16x4 __attribute__((ext_vector_type(4)));
typedef unsigned short u16x8 __attribute__((ext_vector_type(8)));

__device__ __forceinline__ unsigned short f2bf(float f) {
  union { float f; unsigned u; } x; x.f = f;
  unsigned r = x.u + 0x7FFFu + ((x.u >> 16) & 1u);
  return (unsigned short)(r >> 16);
}
__device__ __forceinline__ float bf2f(unsigned short u) {
  union { unsigned u; float f; } x; x.u = ((unsigned)u) << 16;
  return x.f;
}

__device__ __forceinline__ void gl16(const void* g, void* l) {
  __builtin_amdgcn_global_load_lds(
      (const __attribute__((address_space(1))) unsigned*)g,
      (__attribute__((address_space(3))) unsigned*)l, 16, 0, 0);
}

// ---------------- prep: W[k][n] f32 -> WT[n][k] bf16 (4 mats: q,k,v,o) ----
__global__ __launch_bounds__(256) void prep_wt(const float* __restrict__ Wq,
                                               const float* __restrict__ Wk,
                                               const float* __restrict__ Wv,
                                               const float* __restrict__ Wo,
                                               unsigned short* __restrict__ WT) {
  __shared__ unsigned short ts[64][65];
  const float* W = (blockIdx.z == 0) ? Wq : (blockIdx.z == 1) ? Wk
                   : (blockIdx.z == 2) ? Wv : Wo;
  const int t = threadIdx.x;
  const int kbase = blockIdx.y * 64;
  const int nbase = blockIdx.x * 64;
  for (int i = 0; i < 16; ++i) {
    int idx = i * 256 + t;
    int r = idx >> 6, c = idx & 63;
    ts[r][c] = f2bf(W[(size_t)(kbase + r) * 512 + nbase + c]);
  }
  __syncthreads();
  unsigned short* dst = WT + (size_t)blockIdx.z * 512 * 512;
  for (int i = 0; i < 16; ++i) {
    int idx = i * 256 + t;
    int nn = idx >> 6, kk = idx & 63;
    dst[(size_t)(nbase + nn) * 512 + kbase + kk] = ts[kk][nn];
  }
}

__global__ void prep_bias(const float* __restrict__ bq, const float* __restrict__ bk,
                          const float* __restrict__ bv, float* __restrict__ biasc) {
  int i = blockIdx.x * 256 + threadIdx.x;
  if (i < 512) biasc[i] = bq[i];
  else if (i < 1024) biasc[i] = bk[i - 512];
  else if (i < 1536) biasc[i] = bv[i - 1024];
}

// ---------------- 256x256 8-phase GEMM: C = A @ BT^T + bias ---------------
// AT=float: A staged via reg (f32->bf16 cvt fused, T14 split: load p0/p1,
//           cvt+ds_write p2/p3). AT=ushort: gl16 with inverse-swizzled src.
// MFMA operands SWAPPED (B first) -> C/D col=lane&15 is m, reg-dim is n ->
// direct vectorized global stores, no epilogue LDS roundtrip.
template <typename AT, typename CT>
__global__ __launch_bounds__(512, 2) void gemm256(
    const AT* __restrict__ A, int lda,
    const unsigned short* __restrict__ BT,
    CT* __restrict__ C, int ldc,
    const float* __restrict__ bias, int NB) {
  __shared__ alignas(16) unsigned short pool[65536];  // 4 x 16384 (A0,A1,B0,B1)
  const int t = threadIdx.x;
  const int lane = t & 63;
  const int w = t >> 6;
  const int wm = w >> 2, wn = w & 3;

  // XCD-aware bijective swizzle (nwg % 8 == 0 by construction)
  const int nwg = gridDim.x;
  const int cpx = nwg >> 3;
  const int wg = (blockIdx.x & 7) * cpx + (blockIdx.x >> 3);
  const int n0 = (wg % NB) * 256;
  const int m0 = (wg / NB) * 256;

  // ---- staging helpers ----
  const int sr = lane >> 3;
  const int sg = ((lane & 7) ^ sr) << 3;  // inverse-swizzled src granule
  const unsigned short* gB = BT + (size_t)(n0 + w * 8 + sr) * 512 + sg;
  const int lw = w * 512;

  // B: gl16, 2 half-tiles per K-tile. buf b region at pool[32768 + b*16384]
#define SB(kt, h, b)                                                        \
  { const unsigned short* g_ = gB + (size_t)(h) * 128 * 512 + (kt) * 64;    \
    unsigned short* l_ = &pool[32768 + (b) * 16384 + (h) * 8192 + lw];      \
    gl16(g_, l_); gl16(g_ + (size_t)64 * 512, l_ + 4096); }

  // A (ushort path): gl16 like B
  const unsigned short* gAu = nullptr;
  if constexpr (sizeof(AT) == 2)
    gAu = (const unsigned short*)A + (size_t)(m0 + w * 8 + sr) * lda + sg;
#define SA(kt, h, b)                                                        \
  { const unsigned short* g_ = gAu + (size_t)(h) * 128 * lda + (kt) * 64;   \
    unsigned short* l_ = &pool[(b) * 16384 + (h) * 8192 + lw];              \
    gl16(g_, l_); gl16(g_ + (size_t)64 * lda, l_ + 4096); }

  // A (float path): reg-stage. thread t: seg=t&7 (8-elem k-granule),
  // rbase=t>>3; unit u -> row rbase+u*64. ds_write_b128 conflict-free
  // (8-lane groups each cover one full 128-B row).
  f32x4 ar[4][2];
  const int seg = t & 7;
  const int rbase = t >> 3;
  const float* gAf = nullptr;
  if constexpr (sizeof(AT) == 4)
    gAf = (const float*)A + (size_t)(m0 + rbase) * lda + seg * 8;
#define LA(kt, u)                                                           \
  { const float* g_ = gAf + (size_t)(u) * 64 * lda + (kt) * 64;             \
    ar[u][0] = *reinterpret_cast<const f32x4*>(g_);                         \
    ar[u][1] = *reinterpret_cast<const f32x4*>(g_ + 4); }
#define WA(u, b)                                                            \
  { int row_ = rbase + (u) * 64;                                            \
    bf16x8 pk_;                                                             \
    _Pragma("unroll") for (int j_ = 0; j_ < 4; ++j_) {                      \
      pk_[j_] = (__bf16)ar[u][0][j_];                                       \
      pk_[4 + j_] = (__bf16)ar[u][1][j_];                                   \
    }                                                                       \
    *reinterpret_cast<bf16x8*>(                                             \
        &pool[(b) * 16384 + row_ * 64 + ((seg ^ (row_ & 7)) << 3)]) = pk_; }

  // ---- fragment reads (both operands same swizzle -> permutation cancels)
  const int fr = lane & 15;
  const int fg = lane >> 4;
  const int fx = lane & 7;
  auto readA = [&](int b, int mi, int kf) -> bf16x8 {
    return *reinterpret_cast<const bf16x8*>(
        &pool[(b) * 16384 + (wm * 128 + mi * 16 + fr) * 64 +
              ((((kf << 2) + fg) ^ fx) << 3)]);
  };
  auto readB = [&](int b, int ni, int kf) -> bf16x8 {
    return *reinterpret_cast<const bf16x8*>(
        &pool[32768 + (b) * 16384 + (wn * 64 + ni * 16 + fr) * 64 +
              ((((kf << 2) + fg) ^ fx) << 3)]);
  };

  f32x4 acc[8][4];
#pragma unroll
  for (int i = 0; i < 8; ++i)
#pragma unroll
    for (int j = 0; j < 4; ++j) acc[i][j] = (f32x4){0.f, 0.f, 0.f, 0.f};
  bf16x8 bfr[4][2];

// phase: ds-reads | stage | [vmcnt] | bar | lgkm0 | MFMA(swapped)*16 | bar
#define PHASE(b, q, READB, STAGES, VM)                                       \
  {                                                                          \
    bf16x8 a0_ = readA(b, 2 * (q), 0), a1_ = readA(b, 2 * (q), 1);           \
    bf16x8 a2_ = readA(b, 2 * (q) + 1, 0), a3_ = readA(b, 2 * (q) + 1, 1);   \
    if (READB) {                                                             \
      _Pragma("unroll") for (int ni = 0; ni < 4; ++ni) {                     \
        bfr[ni][0] = readB(b, ni, 0);                                        \
        bfr[ni][1] = readB(b, ni, 1);                                        \
      }                                                                      \
    }                                                                        \
    STAGES;                                                                  \
    if ((VM) == 4) asm volatile("s_waitcnt vmcnt(4)" ::: "memory");          \
    if ((VM) == 0) asm volatile("s_waitcnt vmcnt(0)" ::: "memory");          \
    __builtin_amdgcn_s_barrier();                                            \
    asm volatile("s_waitcnt lgkmcnt(0)" ::: "memory");                       \
    __builtin_amdgcn_sched_barrier(0);                                       \
    __builtin_amdgcn_s_setprio(1);                                           \
    _Pragma("unroll") for (int ni = 0; ni < 4; ++ni) {                       \
      acc[2 * (q)][ni] = __builtin_amdgcn_mfma_f32_16x16x32_bf16(            \
          bfr[ni][0], a0_, acc[2 * (q)][ni], 0, 0, 0);                       \
      acc[2 * (q) + 1][ni] = __builtin_amdgcn_mfma_f32_16x16x32_bf16(        \
          bfr[ni][0], a2_, acc[2 * (q) + 1][ni], 0, 0, 0);                   \
    }                                                                        \
    _Pragma("unroll") for (int ni = 0; ni < 4; ++ni) {                       \
      acc[2 * (q)][ni] = __builtin_amdgcn_mfma_f32_16x16x32_bf16(            \
          bfr[ni][1], a1_, acc[2 * (q)][ni], 0, 0, 0);                       \
      acc[2 * (q) + 1][ni] = __builtin_amdgcn_mfma_f32_16x16x32_bf16(        \
          bfr[ni][1], a3_, acc[2 * (q) + 1][ni], 0, 0, 0);                   \
    }                                                                        \
    __builtin_amdgcn_s_setprio(0);                                           \
    __builtin_amdgcn_s_barrier();                                            \
  }

  if constexpr (sizeof(AT) == 4) {
    // prologue: A(0) reg-staged, B(0)+B(1) gl16; drain A-writes + B(0)
    LA(0, 0) LA(0, 1) LA(0, 2) LA(0, 3)
    SB(0, 0, 0) SB(0, 1, 0) SB(1, 0, 1) SB(1, 1, 1)
    WA(0, 0) WA(1, 0) WA(2, 0) WA(3, 0)
    asm volatile("s_waitcnt vmcnt(4) lgkmcnt(0)" ::: "memory");
    __builtin_amdgcn_s_barrier();
#pragma unroll
    for (int i = 0; i < 4; ++i) {
      const bool s2 = (i < 3);
      PHASE(0, 0, true,  { LA(2 * i + 1, 0) LA(2 * i + 1, 1) }, -1);
      PHASE(0, 1, false, { LA(2 * i + 1, 2) LA(2 * i + 1, 3) if (s2) SB(2 * i + 2, 0, 0) }, -1);
      PHASE(0, 2, false, { WA(0, 1) WA(1, 1) if (s2) SB(2 * i + 2, 1, 0) }, -1);
      PHASE(0, 3, false, { WA(2, 1) WA(3, 1) }, s2 ? 4 : 0);
      PHASE(1, 0, true,  { if (s2) { LA(2 * i + 2, 0) LA(2 * i + 2, 1) } }, -1);
      PHASE(1, 1, false, { if (s2) { LA(2 * i + 2, 2) LA(2 * i + 2, 3) SB(2 * i + 3, 0, 1) } }, -1);
      PHASE(1, 2, false, { if (s2) { WA(0, 0) WA(1, 0) SB(2 * i + 3, 1, 1) } }, -1);
      PHASE(1, 3, false, { if (s2) { WA(2, 0) WA(3, 0) } }, s2 ? 4 : 0);
    }
  } else {
    // prologue: t0 fully + t1.B; vmcnt(4) leaves t1.B in flight
    SB(0, 0, 0) SB(0, 1, 0)
    SA(0, 0, 0) SA(0, 1, 0)
    SB(1, 0, 1) SB(1, 1, 1)
    asm volatile("s_waitcnt vmcnt(4)" ::: "memory");
    __builtin_amdgcn_s_barrier();
#pragma unroll
    for (int i = 0; i < 4; ++i) {
      const bool s2 = (i < 3);
      PHASE(0, 0, true,  { SA(2 * i + 1, 0, 1) }, -1);
      PHASE(0, 1, false, { SA(2 * i + 1, 1, 1) if (s2) SB(2 * i + 2, 0, 0) }, -1);
      PHASE(0, 2, false, { if (s2) SB(2 * i + 2, 1, 0) }, -1);
      PHASE(0, 3, false, {}, s2 ? 4 : 0);
      PHASE(1, 0, true,  { if (s2) SA(2 * i + 2, 0, 0) }, -1);
      PHASE(1, 1, false, { if (s2) SA(2 * i + 2, 1, 0) }, -1);
      PHASE(1, 2, false, { if (s2) SB(2 * i + 3, 0, 1) }, -1);
      PHASE(1, 3, false, { if (s2) SB(2 * i + 3, 1, 1) }, s2 ? 4 : 0);
    }
  }
#undef PHASE
#undef SA
#undef SB
#undef LA
#undef WA

  // ---- direct epilogue: lane holds 4 consecutive n-cols (swapped C/D) ----
  // acc[mi][ni][r] = C[m0+wm*128+mi*16+fr][n0+wn*64+ni*16+fg*4+r]
#pragma unroll
  for (int mi = 0; mi < 8; ++mi) {
    const size_t m = (size_t)(m0 + wm * 128 + mi * 16 + fr);
#pragma unroll
    for (int ni = 0; ni < 4; ++ni) {
      const int nb = n0 + wn * 64 + ni * 16 + fg * 4;
      f32x4 b4 = *reinterpret_cast<const f32x4*>(&bias[nb]);
      if constexpr (sizeof(CT) == 2) {
        u16x4 o;
#pragma unroll
        for (int r = 0; r < 4; ++r) o[r] = f2bf(acc[mi][ni][r] + b4[r]);
        *reinterpret_cast<u16x4*>(&C[m * ldc + nb]) = o;
      } else {
        f32x4 o = acc[mi][ni] + b4;
        *reinterpret_cast<f32x4*>(&C[m * ldc + nb]) = o;
      }
    }
  }
}

// ---------------- attention: sigmoid(QK^T/8) @ V per 16-token window ------
__global__ __launch_bounds__(256) void attn_kernel(unsigned short* __restrict__ QKV) {
  __shared__ alignas(16) unsigned short qs[16][1544];
  __shared__ unsigned short ps[8][16][16];
  const int t = threadIdx.x;
  const size_t base = (size_t)blockIdx.x * 16;

  {
    int row = t >> 4;
    int cb = (t & 15) * 96;
    const unsigned short* src = QKV + (base + row) * 1536;
#pragma unroll
    for (int i = 0; i < 24; ++i) {
      int c = cb + i * 4;
      *reinterpret_cast<u16x4*>(&qs[row][c]) = *reinterpret_cast<const u16x4*>(&src[c]);
    }
  }
  __syncthreads();

  const int tq = t >> 4;
  const int tk = t & 15;
#pragma unroll
  for (int h = 0; h < 8; ++h) {
    float acc = 0.f;
#pragma unroll
    for (int dc = 0; dc < 64; dc += 8) {
      u16x8 q8 = *reinterpret_cast<const u16x8*>(&qs[tq][h * 64 + dc]);
      u16x8 k8 = *reinterpret_cast<const u16x8*>(&qs[tk][512 + h * 64 + dc]);
#pragma unroll
      for (int j = 0; j < 8; ++j) acc += bf2f(q8[j]) * bf2f(k8[j]);
    }
    ps[h][tq][tk] = f2bf(1.0f / (1.0f + __expf(-acc * 0.125f)));
  }
  __syncthreads();

  const int row = t >> 4;
  const int cb4 = (t & 15) * 4;
  unsigned short* dst = QKV + (base + row) * 1536 + 1024;
#pragma unroll
  for (int h = 0; h < 8; ++h) {
    f32x4 acc = (f32x4){0.f, 0.f, 0.f, 0.f};
#pragma unroll
    for (int s = 0; s < 16; ++s) {
      float p = bf2f(ps[h][row][s]);
      u16x4 v4 = *reinterpret_cast<const u16x4*>(&qs[s][1024 + h * 64 + cb4]);
      acc[0] += p * bf2f(v4[0]); acc[1] += p * bf2f(v4[1]);
      acc[2] += p * bf2f(v4[2]); acc[3] += p * bf2f(v4[3]);
    }
    u16x4 o4;
    o4[0] = f2bf(acc[0]); o4[1] = f2bf(acc[1]); o4[2] = f2bf(acc[2]); o4[3] = f2bf(acc[3]);
    *reinterpret_cast<u16x4*>(&dst[h * 64 + cb4]) = o4;
  }
}

// --------------------------------------------------------------------------
extern "C" void kernel_launch(void* const* d_in, const int* in_sizes, int n_in,
                              void* d_out, int out_size, void* d_ws, size_t ws_size,
                              hipStream_t stream) {
  const float* x  = (const float*)d_in[0];
  const float* Wq = (const float*)d_in[1];
  const float* bq = (const float*)d_in[2];
  const float* Wk = (const float*)d_in[3];
  const float* bk = (const float*)d_in[4];
  const float* Wv = (const float*)d_in[5];
  const float* bv = (const float*)d_in[6];
  const float* Wo = (const float*)d_in[7];
  const float* bo = (const float*)d_in[8];
  float* out = (float*)d_out;

  const int M = 65536;
  char* ws = (char*)d_ws;
  unsigned short* WT = (unsigned short*)ws;                  // [2048][512] bf16
  float* biasc = (float*)(ws + (size_t)2048 * 512 * 2);      // [1536]
  const long long prep_bytes = (long long)2048 * 512 * 2 + 8192;

  prep_wt<<<dim3(8, 8, 4), 256, 0, stream>>>(Wq, Wk, Wv, Wo, WT);
  prep_bias<<<6, 256, 0, stream>>>(bq, bk, bv, biasc);

  // per-chunk: QKV rows*1536*2 B = rows*3072 B
  long long avail = (long long)ws_size - prep_bytes;
  int chunk_rows = 65536;
  while (chunk_rows > 2048 && (long long)chunk_rows * 3072 > avail) chunk_rows >>= 1;
  const int nchunks = M / chunk_rows;

  unsigned short* QKV = (unsigned short*)(ws + prep_bytes);

  for (int c = 0; c < nchunks; ++c) {
    const size_t row0 = (size_t)c * chunk_rows;
    const int mt = chunk_rows / 256;
    gemm256<float, unsigned short><<<mt * 6, 512, 0, stream>>>(
        x + row0 * 512, 512, WT, QKV, 1536, biasc, 6);
    attn_kernel<<<chunk_rows / 16, 256, 0, stream>>>(QKV);
    gemm256<unsigned short, float><<<mt * 2, 512, 0, stream>>>(
        QKV + 1024, 1536, WT + (size_t)1536 * 512, out + row0 * 512, 512, bo, 2);
  }
}

// Round 8
// 304.462 us; speedup vs baseline: 1.0741x; 1.0741x over previous
//
#include <hip/hip_runtime.h>
#include <hip/hip_bf16.h>

typedef float f32x4 __attribute__((ext_vector_type(4)));
typedef __bf16 bf16x8 __attribute__((ext_vector_type(8)));
typedef unsigned short u16x4 __attribute__((ext_vector_type(4)));
typedef unsigned short u16x8 __attribute__((ext_vector_type(8)));

__device__ __forceinline__ unsigned short f2bf(float f) {
  union { float f; unsigned u; } x; x.f = f;
  unsigned r = x.u + 0x7FFFu + ((x.u >> 16) & 1u);
  return (unsigned short)(r >> 16);
}

__device__ __forceinline__ void gl16(const void* g, void* l) {
  __builtin_amdgcn_global_load_lds(
      (const __attribute__((address_space(1))) unsigned*)g,
      (__attribute__((address_space(3))) unsigned*)l, 16, 0, 0);
}

// ---------------- prep: W[k][n] f32 -> WT[n][k] bf16 (4 mats: q,k,v,o) ----
__global__ __launch_bounds__(256) void prep_wt(const float* __restrict__ Wq,
                                               const float* __restrict__ Wk,
                                               const float* __restrict__ Wv,
                                               const float* __restrict__ Wo,
                                               unsigned short* __restrict__ WT) {
  __shared__ unsigned short ts[64][65];
  const float* W = (blockIdx.z == 0) ? Wq : (blockIdx.z == 1) ? Wk
                   : (blockIdx.z == 2) ? Wv : Wo;
  const int t = threadIdx.x;
  const int kbase = blockIdx.y * 64;
  const int nbase = blockIdx.x * 64;
  for (int i = 0; i < 16; ++i) {
    int idx = i * 256 + t;
    int r = idx >> 6, c = idx & 63;
    ts[r][c] = f2bf(W[(size_t)(kbase + r) * 512 + nbase + c]);
  }
  __syncthreads();
  unsigned short* dst = WT + (size_t)blockIdx.z * 512 * 512;
  for (int i = 0; i < 16; ++i) {
    int idx = i * 256 + t;
    int nn = idx >> 6, kk = idx & 63;
    dst[(size_t)(nbase + nn) * 512 + kbase + kk] = ts[kk][nn];
  }
}

__global__ void prep_bias(const float* __restrict__ bq, const float* __restrict__ bk,
                          const float* __restrict__ bv, float* __restrict__ biasc) {
  int i = blockIdx.x * 256 + threadIdx.x;
  if (i < 512) biasc[i] = bq[i];
  else if (i < 1024) biasc[i] = bk[i - 512];
  else if (i < 1536) biasc[i] = bv[i - 1024];
}

// ---------------- convert X fp32 -> bf16 (streaming) ----------------------
__global__ __launch_bounds__(256) void convert_x(const float* __restrict__ x,
                                                 unsigned short* __restrict__ xb,
                                                 long long n8) {
  long long i = (long long)blockIdx.x * 256 + threadIdx.x;
  const long long stride = (long long)gridDim.x * 256;
  for (; i < n8; i += stride) {
    f32x4 a = *reinterpret_cast<const f32x4*>(&x[i * 8]);
    f32x4 b = *reinterpret_cast<const f32x4*>(&x[i * 8 + 4]);
    u16x8 o;
    o[0] = f2bf(a[0]); o[1] = f2bf(a[1]); o[2] = f2bf(a[2]); o[3] = f2bf(a[3]);
    o[4] = f2bf(b[0]); o[5] = f2bf(b[1]); o[6] = f2bf(b[2]); o[7] = f2bf(b[3]);
    *reinterpret_cast<u16x8*>(&xb[i * 8]) = o;
  }
}

// ---------------- 256x256 8-phase GEMM: C = A @ BT^T + bias ---------------
// A bf16 [M][lda] via gl16 (inverse-swizzled src), BT bf16 [N][512].
// MFMA operands swapped (B first): lane holds 4 consecutive n-cols ->
// direct vectorized stores. Counted vmcnt(4) at phases 4/8.
template <typename CT>
__global__ __launch_bounds__(512, 2) void gemm256(
    const unsigned short* __restrict__ A, int lda,
    const unsigned short* __restrict__ BT,
    CT* __restrict__ C, int ldc,
    const float* __restrict__ bias, int NB) {
  __shared__ alignas(16) unsigned short pool[65536];  // A0|A1|B0|B1 x 16384
  const int t = threadIdx.x;
  const int lane = t & 63;
  const int w = t >> 6;
  const int wm = w >> 2, wn = w & 3;

  const int nwg = gridDim.x;
  const int cpx = nwg >> 3;
  const int wg = (blockIdx.x & 7) * cpx + (blockIdx.x >> 3);
  const int n0 = (wg % NB) * 256;
  const int m0 = (wg / NB) * 256;

  const int sr = lane >> 3;
  const int sg = ((lane & 7) ^ sr) << 3;
  const unsigned short* gA = A + (size_t)(m0 + w * 8 + sr) * lda + sg;
  const unsigned short* gB = BT + (size_t)(n0 + w * 8 + sr) * 512 + sg;
  const int lw = w * 512;

#define SA(kt, h, b)                                                        \
  { const unsigned short* g_ = gA + (size_t)(h) * 128 * lda + (kt) * 64;    \
    unsigned short* l_ = &pool[(b) * 16384 + (h) * 8192 + lw];              \
    gl16(g_, l_); gl16(g_ + (size_t)64 * lda, l_ + 4096); }
#define SB(kt, h, b)                                                        \
  { const unsigned short* g_ = gB + (size_t)(h) * 128 * 512 + (kt) * 64;    \
    unsigned short* l_ = &pool[32768 + (b) * 16384 + (h) * 8192 + lw];      \
    gl16(g_, l_); gl16(g_ + (size_t)64 * 512, l_ + 4096); }

  const int fr = lane & 15;
  const int fg = lane >> 4;
  const int fx = lane & 7;
  auto readA = [&](int b, int mi, int kf) -> bf16x8 {
    return *reinterpret_cast<const bf16x8*>(
        &pool[(b) * 16384 + (wm * 128 + mi * 16 + fr) * 64 +
              ((((kf << 2) + fg) ^ fx) << 3)]);
  };
  auto readB = [&](int b, int ni, int kf) -> bf16x8 {
    return *reinterpret_cast<const bf16x8*>(
        &pool[32768 + (b) * 16384 + (wn * 64 + ni * 16 + fr) * 64 +
              ((((kf << 2) + fg) ^ fx) << 3)]);
  };

  f32x4 acc[8][4];
#pragma unroll
  for (int i = 0; i < 8; ++i)
#pragma unroll
    for (int j = 0; j < 4; ++j) acc[i][j] = (f32x4){0.f, 0.f, 0.f, 0.f};
  bf16x8 bfr[4][2];

#define PHASE(b, q, READB, STAGES, VM)                                       \
  {                                                                          \
    bf16x8 a0_ = readA(b, 2 * (q), 0), a1_ = readA(b, 2 * (q), 1);           \
    bf16x8 a2_ = readA(b, 2 * (q) + 1, 0), a3_ = readA(b, 2 * (q) + 1, 1);   \
    if (READB) {                                                             \
      _Pragma("unroll") for (int ni = 0; ni < 4; ++ni) {                     \
        bfr[ni][0] = readB(b, ni, 0);                                        \
        bfr[ni][1] = readB(b, ni, 1);                                        \
      }                                                                      \
    }                                                                        \
    STAGES;                                                                  \
    if ((VM) == 4) asm volatile("s_waitcnt vmcnt(4)" ::: "memory");          \
    if ((VM) == 0) asm volatile("s_waitcnt vmcnt(0)" ::: "memory");          \
    __builtin_amdgcn_s_barrier();                                            \
    asm volatile("s_waitcnt lgkmcnt(0)" ::: "memory");                       \
    __builtin_amdgcn_sched_barrier(0);                                       \
    __builtin_amdgcn_s_setprio(1);                                           \
    _Pragma("unroll") for (int ni = 0; ni < 4; ++ni) {                       \
      acc[2 * (q)][ni] = __builtin_amdgcn_mfma_f32_16x16x32_bf16(            \
          bfr[ni][0], a0_, acc[2 * (q)][ni], 0, 0, 0);                       \
      acc[2 * (q) + 1][ni] = __builtin_amdgcn_mfma_f32_16x16x32_bf16(        \
          bfr[ni][0], a2_, acc[2 * (q) + 1][ni], 0, 0, 0);                   \
    }                                                                        \
    _Pragma("unroll") for (int ni = 0; ni < 4; ++ni) {                       \
      acc[2 * (q)][ni] = __builtin_amdgcn_mfma_f32_16x16x32_bf16(            \
          bfr[ni][1], a1_, acc[2 * (q)][ni], 0, 0, 0);                       \
      acc[2 * (q) + 1][ni] = __builtin_amdgcn_mfma_f32_16x16x32_bf16(        \
          bfr[ni][1], a3_, acc[2 * (q) + 1][ni], 0, 0, 0);                   \
    }                                                                        \
    __builtin_amdgcn_s_setprio(0);                                           \
    __builtin_amdgcn_s_barrier();                                            \
  }

  SB(0, 0, 0) SB(0, 1, 0)
  SA(0, 0, 0) SA(0, 1, 0)
  SB(1, 0, 1) SB(1, 1, 1)
  asm volatile("s_waitcnt vmcnt(4)" ::: "memory");
  __builtin_amdgcn_s_barrier();

#pragma unroll
  for (int i = 0; i < 4; ++i) {
    const bool s2 = (i < 3);
    PHASE(0, 0, true,  { SA(2 * i + 1, 0, 1) }, -1);
    PHASE(0, 1, false, { SA(2 * i + 1, 1, 1) if (s2) SB(2 * i + 2, 0, 0) }, -1);
    PHASE(0, 2, false, { if (s2) SB(2 * i + 2, 1, 0) }, -1);
    PHASE(0, 3, false, {}, s2 ? 4 : 0);
    PHASE(1, 0, true,  { if (s2) SA(2 * i + 2, 0, 0) }, -1);
    PHASE(1, 1, false, { if (s2) SA(2 * i + 2, 1, 0) }, -1);
    PHASE(1, 2, false, { if (s2) SB(2 * i + 3, 0, 1) }, -1);
    PHASE(1, 3, false, { if (s2) SB(2 * i + 3, 1, 1) }, s2 ? 4 : 0);
  }
#undef PHASE
#undef SA
#undef SB

  // direct epilogue: acc[mi][ni][r] = C[m0+wm*128+mi*16+fr][n0+wn*64+ni*16+fg*4+r]
#pragma unroll
  for (int mi = 0; mi < 8; ++mi) {
    const size_t m = (size_t)(m0 + wm * 128 + mi * 16 + fr);
#pragma unroll
    for (int ni = 0; ni < 4; ++ni) {
      const int nb = n0 + wn * 64 + ni * 16 + fg * 4;
      f32x4 b4 = *reinterpret_cast<const f32x4*>(&bias[nb]);
      if constexpr (sizeof(CT) == 2) {
        u16x4 o;
#pragma unroll
        for (int r = 0; r < 4; ++r) o[r] = f2bf(acc[mi][ni][r] + b4[r]);
        *reinterpret_cast<u16x4*>(&C[m * ldc + nb]) = o;
      } else {
        f32x4 o = acc[mi][ni] + b4;
        *reinterpret_cast<f32x4*>(&C[m * ldc + nb]) = o;
      }
    }
  }
}

// ---------------- MFMA attention: sigmoid(QK^T/8) @ V --------------------
// Block = 256 thr (4 waves) owns 8 windows. Per head: stage Q,K (swizzled)
// + V (linear) via gl16; wave does 2 windows. S^T = mfma(K,Q): lane holds
// S[q=fr][s=fg*4+r] -> sigmoid -> P via tiny per-wave LDS tile ps[q][s]
// (same-wave in-order LDS, no barrier) -> PV with the SAME verified
// 16x16x32 builtin, K zero-padded: B-fragment = P^T for fg<2, zeros for
// fg>=2 (kills k=16..31 slices); A-fragment = V^T per-lane scalar reads.
// Output ctx^T -> lane holds 4 consecutive d -> u16x4 store.
__global__ __launch_bounds__(256) void attn_mfma(unsigned short* __restrict__ QKV) {
  __shared__ alignas(16) unsigned short sh[24576];  // Q[8192] K[8192] V[8192]
  __shared__ alignas(16) unsigned short ps[1024];   // per-wave 16x16 P tile
  const int t = threadIdx.x;
  const int lane = t & 63;
  const int w = t >> 6;
  const int fr = lane & 15, fg = lane >> 4, fx = lane & 7;
  const size_t base = (size_t)blockIdx.x * 128;
  const int srw = lane >> 3;   // staging row within 8-row chunk
  const int sgq = lane & 7;    // staging granule

  for (int h = 0; h < 8; ++h) {
    // ---- stage head h: Q,K swizzled; V linear ----
#pragma unroll
    for (int i = 0; i < 4; ++i) {
      const int c = i * 4 + w;             // 16 chunks of 1KB per matrix
      const int win = c >> 1;
      const int row = (c & 1) * 8 + srw;   // 0..15 within window
      const unsigned short* srow =
          QKV + (base + win * 16 + row) * 1536 + h * 64;
      const int gsw = (sgq ^ (row & 7)) << 3;
      gl16(srow + gsw,               &sh[c * 512]);
      gl16(srow + 512 + gsw,         &sh[8192 + c * 512]);
      gl16(srow + 1024 + (sgq << 3), &sh[16384 + c * 512]);
    }
    asm volatile("s_waitcnt vmcnt(0)" ::: "memory");
    __syncthreads();
    // ---- compute: 2 windows per wave ----
#pragma unroll
    for (int ww = 0; ww < 2; ++ww) {
      const int wi = w * 2 + ww;
      const int qb = wi * 1024;
      f32x4 s = (f32x4){0.f, 0.f, 0.f, 0.f};
#pragma unroll
      for (int kk = 0; kk < 2; ++kk) {
        const int go = ((((kk << 2) + fg) ^ fx) << 3);
        bf16x8 kf = *reinterpret_cast<const bf16x8*>(&sh[8192 + qb + fr * 64 + go]);
        bf16x8 qf = *reinterpret_cast<const bf16x8*>(&sh[qb + fr * 64 + go]);
        s = __builtin_amdgcn_mfma_f32_16x16x32_bf16(kf, qf, s, 0, 0, 0);
      }
      // lane holds S[q=fr][s=fg*4+r] -> sigmoid -> stash into ps[q][s]
      u16x4 pfu;
#pragma unroll
      for (int r = 0; r < 4; ++r)
        pfu[r] = f2bf(1.0f / (1.0f + __expf(-s[r] * 0.125f)));
      *reinterpret_cast<u16x4*>(&ps[w * 256 + fr * 16 + fg * 4]) = pfu;
      // B-fragment: P^T rows k=fg*8+j (fg<2), zeros for k>=16
      u16x8 pbu = (u16x8){0, 0, 0, 0, 0, 0, 0, 0};
      if (fg < 2)
        pbu = *reinterpret_cast<const u16x8*>(&ps[w * 256 + fr * 16 + fg * 8]);
      bf16x8 pb = __builtin_bit_cast(bf16x8, pbu);
#pragma unroll
      for (int dc = 0; dc < 4; ++dc) {
        u16x8 vau;
#pragma unroll
        for (int j = 0; j < 8; ++j)
          vau[j] = sh[16384 + qb + ((fg & 1) * 8 + j) * 64 + dc * 16 + fr];
        bf16x8 va = __builtin_bit_cast(bf16x8, vau);
        f32x4 c = __builtin_amdgcn_mfma_f32_16x16x32_bf16(
            va, pb, (f32x4){0.f, 0.f, 0.f, 0.f}, 0, 0, 0);
        u16x4 o;
#pragma unroll
        for (int r = 0; r < 4; ++r) o[r] = f2bf(c[r]);
        *reinterpret_cast<u16x4*>(
            &QKV[(base + wi * 16 + fr) * 1536 + 1024 + h * 64 + dc * 16 + fg * 4]) = o;
      }
    }
    __syncthreads();
  }
}

// --------------------------------------------------------------------------
extern "C" void kernel_launch(void* const* d_in, const int* in_sizes, int n_in,
                              void* d_out, int out_size, void* d_ws, size_t ws_size,
                              hipStream_t stream) {
  const float* x  = (const float*)d_in[0];
  const float* Wq = (const float*)d_in[1];
  const float* bq = (const float*)d_in[2];
  const float* Wk = (const float*)d_in[3];
  const float* bk = (const float*)d_in[4];
  const float* Wv = (const float*)d_in[5];
  const float* bv = (const float*)d_in[6];
  const float* Wo = (const float*)d_in[7];
  const float* bo = (const float*)d_in[8];
  float* out = (float*)d_out;

  const int M = 65536;
  char* ws = (char*)d_ws;
  unsigned short* WT = (unsigned short*)ws;                  // [2048][512] bf16
  float* biasc = (float*)(ws + (size_t)2048 * 512 * 2);      // [1536]
  const long long prep_bytes = (long long)2048 * 512 * 2 + 8192;

  prep_wt<<<dim3(8, 8, 4), 256, 0, stream>>>(Wq, Wk, Wv, Wo, WT);
  prep_bias<<<6, 256, 0, stream>>>(bq, bk, bv, biasc);

  // per-chunk: Xb rows*512*2 + QKV rows*1536*2 = rows*4096 B
  long long avail = (long long)ws_size - prep_bytes;
  int chunk_rows = 65536;
  while (chunk_rows > 2048 && (long long)chunk_rows * 4096 > avail) chunk_rows >>= 1;
  const int nchunks = M / chunk_rows;

  unsigned short* Xb  = (unsigned short*)(ws + prep_bytes);
  unsigned short* QKV = Xb + (size_t)chunk_rows * 512;

  for (int c = 0; c < nchunks; ++c) {
    const size_t row0 = (size_t)c * chunk_rows;
    const int mt = chunk_rows / 256;
    convert_x<<<2048, 256, 0, stream>>>(x + row0 * 512, Xb,
                                        (long long)chunk_rows * 64);
    gemm256<unsigned short><<<mt * 6, 512, 0, stream>>>(
        Xb, 512, WT, QKV, 1536, biasc, 6);
    attn_mfma<<<chunk_rows / 128, 256, 0, stream>>>(QKV);
    gemm256<float><<<mt * 2, 512, 0, stream>>>(
        QKV + 1024, 1536, WT + (size_t)1536 * 512, out + row0 * 512, 512, bo, 2);
  }
}